// Round 5
// baseline (306.393 us; speedup 1.0000x reference)
//
#include <hip/hip_runtime.h>
#include <math.h>

#define B     16
#define CIN   32
#define COUT  32
#define G     256
#define NSITE 512   // 32 kx-modes * 16 ky-modes

// ---------------------------------------------------------------------------
// ws layout (float2 units):
//   tw   : [256]            (pad to 512)        2 KB
//   wt   : [512][1024]      weights by site     4 MB
//   T    : [512][16][256]   ny-DFT result      16 MB
//   X    : [512][512]       [site][b*32+i]      2 MB
//   Y    : [512][512]       [b*32+o][site]      2 MB
// total ~24.1 MB
// ---------------------------------------------------------------------------

// twiddle init: tw[m] = (cos, sin)(2*pi*m/256), f64-accurate. One block.
__global__ void k_init(float2* __restrict__ tw) {
    int t = threadIdx.x;
    double ang = (double)t * (M_PI / 128.0);
    tw[t] = make_float2((float)cos(ang), (float)sin(ang));
}

// weight transpose: wt[half*256 + s][io] = (wr[io*256+s], wi[io*256+s])
// grid (16,4,2): io-tile 64, s-tile 64, half. LDS-tiled, both sides coalesced.
__global__ __launch_bounds__(256) void k_wt(const float* __restrict__ w1r,
                                            const float* __restrict__ w1i,
                                            const float* __restrict__ w2r,
                                            const float* __restrict__ w2i,
                                            float2* __restrict__ wt) {
    __shared__ float2 ts[64][65];
    const int t = threadIdx.x;
    const int io0 = blockIdx.x * 64;
    const int s0  = blockIdx.y * 64;
    const int half = blockIdx.z;
    const float* wr = half ? w2r : w1r;
    const float* wi = half ? w2i : w1i;
    #pragma unroll
    for (int j = 0; j < 16; ++j) {
        int e = j * 256 + t;                 // 0..4095
        int iol = e >> 6, sl = e & 63;       // consecutive t -> consecutive s: coalesced
        size_t src = (size_t)(io0 + iol) * 256 + s0 + sl;
        ts[sl][iol] = make_float2(wr[src], wi[src]);
    }
    __syncthreads();
    #pragma unroll
    for (int j = 0; j < 16; ++j) {
        int e = j * 256 + t;
        int srow = e >> 6, iol = e & 63;     // consecutive t -> consecutive io: coalesced
        wt[(size_t)(half * 256 + s0 + srow) * 1024 + io0 + iol] = ts[srow][iol];
    }
}

// ---------------------------------------------------------------------------
// Forward ny-DFT (radix-2 over ny), 64 nx-rows per block. Grid 2048.
// T[k](nx) = sum_{m<128} conj(tw[k*m]) * (ev|od), ev/od = x[m] +/- x[m+128].
// Thread (r = t&63, g = t>>6) owns row nx = 64q+r, k in {4g..4g+3}.
// Twiddles: exact LDS table reads (wave-uniform -> broadcast), no rotators.
// LDS 10.7 KB -> ~6 blocks/CU.
// ---------------------------------------------------------------------------
__global__ __launch_bounds__(256, 6) void k_fwdA(const float* __restrict__ x,
                                                 const float2* __restrict__ twg,
                                                 float2* __restrict__ T) {
    __shared__ float2 tw[256];          // 2 KB
    __shared__ float tile[32][68];      // 8.7 KB; cols 0-15: ny=m0+e, 16-31: ny=m0+128+e
    const int t = threadIdx.x;
    tw[t] = twg[t];
    const int img = blockIdx.x >> 2, q = blockIdx.x & 3;
    const float* xp = x + (size_t)img * (G * G) + (size_t)(q * 64) * G;
    const int r = t & 63;
    const int g = __builtin_amdgcn_readfirstlane(t >> 6);
    const int kbase = 4 * g;
    const int rr = (t >> 2) & 63, sg = t & 3;   // staging: row rr, float4-seg sg

    float tr0 = 0.f, ti0 = 0.f, tr1 = 0.f, ti1 = 0.f;
    float tr2 = 0.f, ti2 = 0.f, tr3 = 0.f, ti3 = 0.f;

    // stage chunk 0: ny in [0,16) u [128,144)
    float4 f0 = *reinterpret_cast<const float4*>(xp + (size_t)rr * G + 4 * sg);
    float4 f1 = *reinterpret_cast<const float4*>(xp + (size_t)rr * G + 128 + 4 * sg);
    tile[4 * sg + 0][rr] = f0.x; tile[4 * sg + 1][rr] = f0.y;
    tile[4 * sg + 2][rr] = f0.z; tile[4 * sg + 3][rr] = f0.w;
    tile[16 + 4 * sg + 0][rr] = f1.x; tile[16 + 4 * sg + 1][rr] = f1.y;
    tile[16 + 4 * sg + 2][rr] = f1.z; tile[16 + 4 * sg + 3][rr] = f1.w;
    __syncthreads();

    for (int c = 0; c < 8; ++c) {
        const int m0 = c * 16;
        if (c < 7) {   // issue next chunk's loads before compute
            f0 = *reinterpret_cast<const float4*>(xp + (size_t)rr * G + (m0 + 16) + 4 * sg);
            f1 = *reinterpret_cast<const float4*>(xp + (size_t)rr * G + (m0 + 144) + 4 * sg);
        }
        int i0 = ((kbase + 0) * m0) & 255, i1 = ((kbase + 1) * m0) & 255;
        int i2 = ((kbase + 2) * m0) & 255, i3 = ((kbase + 3) * m0) & 255;
        #pragma unroll
        for (int e = 0; e < 16; ++e) {
            float x0 = tile[e][r], x1 = tile[16 + e][r];
            float ev = x0 + x1, od = x0 - x1;
            float2 w0 = tw[i0], w1 = tw[i1], w2 = tw[i2], w3 = tw[i3];
            tr0 = fmaf(ev, w0.x, tr0); ti0 = fmaf(ev, -w0.y, ti0);
            tr1 = fmaf(od, w1.x, tr1); ti1 = fmaf(od, -w1.y, ti1);
            tr2 = fmaf(ev, w2.x, tr2); ti2 = fmaf(ev, -w2.y, ti2);
            tr3 = fmaf(od, w3.x, tr3); ti3 = fmaf(od, -w3.y, ti3);
            i0 = (i0 + kbase + 0) & 255; i1 = (i1 + kbase + 1) & 255;
            i2 = (i2 + kbase + 2) & 255; i3 = (i3 + kbase + 3) & 255;
        }
        __syncthreads();
        if (c < 7) {
            tile[4 * sg + 0][rr] = f0.x; tile[4 * sg + 1][rr] = f0.y;
            tile[4 * sg + 2][rr] = f0.z; tile[4 * sg + 3][rr] = f0.w;
            tile[16 + 4 * sg + 0][rr] = f1.x; tile[16 + 4 * sg + 1][rr] = f1.y;
            tile[16 + 4 * sg + 2][rr] = f1.z; tile[16 + 4 * sg + 3][rr] = f1.w;
            __syncthreads();
        }
    }
    // T[img][k][nx], coalesced per j
    float2* Tp = T + ((size_t)img * 16 + kbase) * G + q * 64;
    Tp[0 * G + r] = make_float2(tr0, ti0);
    Tp[1 * G + r] = make_float2(tr1, ti1);
    Tp[2 * G + r] = make_float2(tr2, ti2);
    Tp[3 * G + r] = make_float2(tr3, ti3);
}

// ---------------------------------------------------------------------------
// Forward nx-DFT (radix-2 over nx). One block per image; round-4 phase-B body.
// X[site][b*32+i] (scattered 8B writes, small).
// ---------------------------------------------------------------------------
__global__ __launch_bounds__(256) void k_fwdB(const float2* __restrict__ T,
                                              const float2* __restrict__ twg,
                                              float2* __restrict__ X) {
    __shared__ float2 tw[256];
    __shared__ float2 Tl[16][258];      // [ky][nx], 33 KB
    const int t = threadIdx.x;
    tw[t] = twg[t];
    const int img = blockIdx.x;
    const float2* Tp = T + (size_t)img * 16 * G;
    #pragma unroll
    for (int j = 0; j < 8; ++j) {       // 2048 float4, coalesced
        int e = j * 256 + t;
        float4 v = reinterpret_cast<const float4*>(Tp)[e];
        int ky_ = e >> 7, c2 = (e & 127) * 2;
        Tl[ky_][c2]     = make_float2(v.x, v.y);
        Tl[ky_][c2 + 1] = make_float2(v.z, v.w);
    }
    __syncthreads();

    const int ky = t & 15, kxg = t >> 4;    // outputs: kx = kxg and 240+kxg
    float x1r = 0.f, x1i = 0.f, x2r = 0.f, x2i = 0.f;
    const float sgn = 1.f - 2.f * (float)(kxg & 1);
    const float s1r = tw[kxg].x,      s1i = -tw[kxg].y;
    const float s2r = tw[16 - kxg].x, s2i =  tw[16 - kxg].y;
    for (int c2 = 0; c2 < 4; ++c2) {
        const int nx0 = c2 * 32;
        int e1 = (kxg * nx0) & 255;
        float w1r_ = tw[e1].x, w1i_ = -tw[e1].y;
        int e2 = ((16 - kxg) * nx0) & 255;
        float w2r_ = tw[e2].x, w2i_ = tw[e2].y;
        #pragma unroll
        for (int j = 0; j < 32; ++j) {
            float2 a = Tl[ky][nx0 + j];
            float2 b = Tl[ky][128 + nx0 + j];
            float pr = fmaf(sgn, b.x, a.x);
            float pi = fmaf(sgn, b.y, a.y);
            x1r = fmaf(pr, w1r_, fmaf(-pi, w1i_, x1r));
            x1i = fmaf(pr, w1i_, fmaf( pi, w1r_, x1i));
            x2r = fmaf(pr, w2r_, fmaf(-pi, w2i_, x2r));
            x2i = fmaf(pr, w2i_, fmaf( pi, w2r_, x2i));
            float n1 = fmaf(w1r_, s1r, -w1i_ * s1i);
            w1i_     = fmaf(w1r_, s1i,  w1i_ * s1r);
            w1r_ = n1;
            float n2 = fmaf(w2r_, s2r, -w2i_ * s2i);
            w2i_     = fmaf(w2r_, s2i,  w2i_ * s2r);
            w2r_ = n2;
        }
    }
    X[(size_t)(kxg * 16 + ky) * 512 + img]        = make_float2(x1r, x1i);
    X[(size_t)((kxg + 16) * 16 + ky) * 512 + img] = make_float2(x2r, x2i);
}

// ---------------------------------------------------------------------------
// Channel mix. One block per site. X and wt reads fully contiguous;
// Y[b*32+o][site] writes scattered 8B (4 KB/block total).
// ---------------------------------------------------------------------------
__global__ __launch_bounds__(256) void k_mix(const float2* __restrict__ X,
                                             const float2* __restrict__ wt,
                                             float2* __restrict__ Y) {
    __shared__ float2 Ws[CIN * COUT];   // [i*32+o], 8 KB
    __shared__ float2 Xs[B * CIN];      // [b*32+i], 4 KB
    const int t = threadIdx.x;
    const int site = blockIdx.x;
    const float2* wp = wt + (size_t)site * 1024;
    const float2* xp = X + (size_t)site * 512;
    reinterpret_cast<float4*>(Ws)[t]       = reinterpret_cast<const float4*>(wp)[t];
    reinterpret_cast<float4*>(Ws)[t + 256] = reinterpret_cast<const float4*>(wp)[t + 256];
    if (t < 256) reinterpret_cast<float4*>(Xs)[t] = reinterpret_cast<const float4*>(xp)[t];
    __syncthreads();
    #pragma unroll
    for (int p = t; p < B * COUT; p += 256) {
        int bb = p >> 5, o = p & 31;
        float yr = 0.f, yi = 0.f;
        #pragma unroll
        for (int i = 0; i < CIN; ++i) {
            float2 xv = Xs[bb * 32 + i];
            float2 wv = Ws[i * 32 + o];
            yr = fmaf(xv.x, wv.x, fmaf(-xv.y, wv.y, yr));
            yi = fmaf(xv.x, wv.y, fmaf( xv.y, wv.x, yi));
        }
        Y[(size_t)(bb * COUT + o) * NSITE + site] = make_float2(yr, yi);
    }
}

// ---------------------------------------------------------------------------
// Inverse, 4-way nx-split (round-4 body; tw staged from global).
// ---------------------------------------------------------------------------
__global__ __launch_bounds__(256, 4) void k_inv(const float2* __restrict__ Y,
                                                const float2* __restrict__ twg,
                                                float* __restrict__ out) {
    __shared__ float2 tw[256];
    __shared__ __align__(16) float2 Ys[32][16];   // 4 KB
    __shared__ __align__(16) float2 U[64][18];    // 9.2 KB
    const int t = threadIdx.x;
    tw[t] = twg[t];
    const int img = blockIdx.x >> 2, Q = blockIdx.x & 3;
    const float2* yp = Y + (size_t)img * NSITE;
    reinterpret_cast<float4*>(Ys)[t] = reinterpret_cast<const float4*>(yp)[t];
    __syncthreads();

    // ---- phase 1 ----
    const int nxl = t & 63, kg = t >> 6;
    const int nx = Q * 64 + nxl;
    float ur[4], ui[4];
    #pragma unroll
    for (int j = 0; j < 4; ++j) { ur[j] = 0.f; ui[j] = 0.f; }
    const float str = tw[nx].x, sti = tw[nx].y;   // e^{+2pi i nx/256}
    float wr = 1.f, wi = 0.f;
    #pragma unroll 4
    for (int kxi = 0; kxi < 16; ++kxi) {
        float4 a = reinterpret_cast<const float4*>(Ys[kxi])[2 * kg];
        float4 b = reinterpret_cast<const float4*>(Ys[kxi])[2 * kg + 1];
        ur[0] = fmaf(a.x, wr, fmaf(-a.y, wi, ur[0])); ui[0] = fmaf(a.x, wi, fmaf(a.y, wr, ui[0]));
        ur[1] = fmaf(a.z, wr, fmaf(-a.w, wi, ur[1])); ui[1] = fmaf(a.z, wi, fmaf(a.w, wr, ui[1]));
        ur[2] = fmaf(b.x, wr, fmaf(-b.y, wi, ur[2])); ui[2] = fmaf(b.x, wi, fmaf(b.y, wr, ui[2]));
        ur[3] = fmaf(b.z, wr, fmaf(-b.w, wi, ur[3])); ui[3] = fmaf(b.z, wi, fmaf(b.w, wr, ui[3]));
        float nr = fmaf(wr, str, -wi * sti); wi = fmaf(wr, sti, wi * str); wr = nr;
    }
    {   // restart at kx=240: w = e^{-2pi i 16 nx/256}
        int e = (16 * nx) & 255;
        wr = tw[e].x; wi = -tw[e].y;
    }
    #pragma unroll 4
    for (int kxi = 16; kxi < 32; ++kxi) {
        float4 a = reinterpret_cast<const float4*>(Ys[kxi])[2 * kg];
        float4 b = reinterpret_cast<const float4*>(Ys[kxi])[2 * kg + 1];
        ur[0] = fmaf(a.x, wr, fmaf(-a.y, wi, ur[0])); ui[0] = fmaf(a.x, wi, fmaf(a.y, wr, ui[0]));
        ur[1] = fmaf(a.z, wr, fmaf(-a.w, wi, ur[1])); ui[1] = fmaf(a.z, wi, fmaf(a.w, wr, ui[1]));
        ur[2] = fmaf(b.x, wr, fmaf(-b.y, wi, ur[2])); ui[2] = fmaf(b.x, wi, fmaf(b.y, wr, ui[2]));
        ur[3] = fmaf(b.z, wr, fmaf(-b.w, wi, ur[3])); ui[3] = fmaf(b.z, wi, fmaf(b.w, wr, ui[3]));
        float nr = fmaf(wr, str, -wi * sti); wi = fmaf(wr, sti, wi * str); wr = nr;
    }
    #pragma unroll
    for (int j = 0; j < 4; ++j) U[nxl][4 * kg + j] = make_float2(ur[j], ui[j]);
    __syncthreads();

    // ---- phase 2 ----
    const int wv = t >> 6, ln = t & 63;
    float tc[16], ts[16];
    #pragma unroll
    for (int k = 1; k < 16; ++k) {
        float2 w = tw[(k * ln) & 255];
        tc[k] = 2.f * w.x; ts[k] = 2.f * w.y;
    }
    float* op = out + (size_t)img * (G * G);
    for (int r = 0; r < 16; ++r) {
        const int rl = wv * 16 + r;
        const int nxg = Q * 64 + rl;
        float4 u[8];
        #pragma unroll
        for (int q = 0; q < 8; ++q)
            u[q] = reinterpret_cast<const float4*>(U[rl])[q];   // broadcast
        #pragma unroll
        for (int nb = 0; nb < 4; ++nb) {
            float acc = u[0].x;
            #pragma unroll
            for (int k = 1; k < 16; ++k) {
                float urk = (k & 1) ? u[k >> 1].z : u[k >> 1].x;
                float uik = (k & 1) ? u[k >> 1].w : u[k >> 1].y;
                const int m = (k * nb) & 3;
                if (m == 0)      acc = fmaf(urk, tc[k], fmaf(-uik, ts[k], acc));
                else if (m == 1) acc = fmaf(-urk, ts[k], fmaf(-uik, tc[k], acc));
                else if (m == 2) acc = fmaf(-urk, tc[k], fmaf( uik, ts[k], acc));
                else             acc = fmaf( urk, ts[k], fmaf( uik, tc[k], acc));
            }
            op[(size_t)nxg * G + nb * 64 + ln] = acc * (1.0f / 65536.0f);
        }
    }
}

extern "C" void kernel_launch(void* const* d_in, const int* in_sizes, int n_in,
                              void* d_out, int out_size, void* d_ws, size_t ws_size,
                              hipStream_t stream) {
    const float* x   = (const float*)d_in[0];
    const float* w1r = (const float*)d_in[1];
    const float* w1i = (const float*)d_in[2];
    const float* w2r = (const float*)d_in[3];
    const float* w2i = (const float*)d_in[4];
    float* out = (float*)d_out;

    float2* tw = (float2*)d_ws;              // 512 float2 (256 used)
    float2* wt = tw + 512;                   // 512*1024
    float2* T  = wt + 512 * 1024;            // 512*16*256
    float2* X  = T  + 512 * 16 * 256;        // 512*512
    float2* Y  = X  + 512 * 512;             // 512*512

    k_init<<<dim3(1),          dim3(256), 0, stream>>>(tw);
    k_wt  <<<dim3(16, 4, 2),   dim3(256), 0, stream>>>(w1r, w1i, w2r, w2i, wt);
    k_fwdA<<<dim3(B * CIN * 4), dim3(256), 0, stream>>>(x, tw, T);
    k_fwdB<<<dim3(B * CIN),    dim3(256), 0, stream>>>(T, tw, X);
    k_mix <<<dim3(NSITE),      dim3(256), 0, stream>>>(X, wt, Y);
    k_inv <<<dim3(B * COUT * 4), dim3(256), 0, stream>>>(Y, tw, out);
}